// Round 1
// baseline (131.305 us; speedup 1.0000x reference)
//
#include <hip/hip_runtime.h>

#define B_ 8
#define A_ 98304
#define C_ 80
#define M_ 32
#define BLK 256

// loss term for one class probability.
// target==1 : 0.25*(1-p)^2 * (-log p)
// target==0 : 0.75*p^2     * (-log(1-p))
// unified: q = t1 ? p : 1-p ; a = t1 ? .25 : .75 ; loss = a*(1-q)^2*(-log q)
__device__ __forceinline__ float focal_term(float praw, bool is_one) {
    float p = fminf(fmaxf(praw, 1e-4f), 1.0f - 1e-4f);
    float q = is_one ? p : (1.0f - p);
    float a = is_one ? 0.25f : 0.75f;
    float om = 1.0f - q;
    return a * om * om * (-__logf(q));
}

__device__ __forceinline__ float smooth_l1(float t, float r) {
    float d = fabsf(t - r);
    return (d <= (1.0f / 9.0f)) ? (0.5f * 9.0f * d * d) : (d - 0.5f / 9.0f);
}

__global__ __launch_bounds__(BLK) void focal_main(
    const float* __restrict__ cls,      // [B,A,C]
    const float* __restrict__ regr,     // [B,A,4]
    const float* __restrict__ anchors,  // [A,4] (leading 1 dropped)
    const float* __restrict__ ann,      // [B,M,5]
    const float* __restrict__ neg_thr_p,
    const float* __restrict__ pos_thr_p,
    float* __restrict__ acc)            // [B,3] : cls_sum, reg_sum, num_pos
{
    __shared__ float s_ann[M_ * 5];
    __shared__ int   s_state[BLK];      // -1 ignore, -2 negative, >=0 assigned class (pos)
    __shared__ float s_red[(BLK / 64) * 3];

    const int tid = threadIdx.x;
    const int blocksPerImg = A_ / BLK;  // 384
    const int b  = blockIdx.x / blocksPerImg;
    const int a0 = (blockIdx.x % blocksPerImg) * BLK;

    if (tid < M_ * 5) s_ann[tid] = ann[b * M_ * 5 + tid];
    __syncthreads();

    const float neg_thr = neg_thr_p[0];
    const float pos_thr = pos_thr_p[0];

    // ---- phase 1: per-anchor IoU assignment + regression loss ----
    const int a = a0 + tid;
    const float4 an = reinterpret_cast<const float4*>(anchors)[a];
    const float aw = an.z - an.x;
    const float ah = an.w - an.y;
    const float areaA = aw * ah;

    float iou_max = -1e30f;
    int   arg = 0;
#pragma unroll
    for (int m = 0; m < M_; ++m) {
        const float bx0 = s_ann[m * 5 + 0];
        const float by0 = s_ann[m * 5 + 1];
        const float bx1 = s_ann[m * 5 + 2];
        const float by1 = s_ann[m * 5 + 3];
        const float areaB = (bx1 - bx0) * (by1 - by0);
        const float iw = fmaxf(fminf(an.z, bx1) - fmaxf(an.x, bx0), 0.0f);
        const float ih = fmaxf(fminf(an.w, by1) - fmaxf(an.y, by0), 0.0f);
        const float inter = iw * ih;
        const float ua = fmaxf(areaA + areaB - inter, 1e-8f);
        float iou = inter / ua;
        if (s_ann[m * 5 + 4] == -1.0f) iou = -1.0f;   // invalid annotation
        if (iou > iou_max) { iou_max = iou; arg = m; }
    }

    const bool pos = (iou_max >= pos_thr);
    const bool neg = (iou_max <  neg_thr);

    float reg_partial = 0.0f;
    float pos_count   = 0.0f;
    int   state       = -1;               // ignore by default
    if (pos) {
        const float gx0 = s_ann[arg * 5 + 0];
        const float gy0 = s_ann[arg * 5 + 1];
        const float gx1 = s_ann[arg * 5 + 2];
        const float gy1 = s_ann[arg * 5 + 3];
        state = (int)s_ann[arg * 5 + 4];
        pos_count = 1.0f;

        float gw = gx1 - gx0;
        float gh = gy1 - gy0;
        const float gcx = gx0 + 0.5f * gw;
        const float gcy = gy0 + 0.5f * gh;
        gw = fmaxf(gw, 1.0f);
        gh = fmaxf(gh, 1.0f);
        const float acx = an.x + 0.5f * aw;
        const float acy = an.y + 0.5f * ah;

        const float t0 = ((gcx - acx) / aw) / 0.1f;
        const float t1 = ((gcy - acy) / ah) / 0.1f;
        const float t2 = logf(gw / aw) / 0.2f;
        const float t3 = logf(gh / ah) / 0.2f;

        const float4 r = reinterpret_cast<const float4*>(regr)[(size_t)b * A_ + a];
        reg_partial = smooth_l1(t0, r.x) + smooth_l1(t1, r.y) +
                      smooth_l1(t2, r.z) + smooth_l1(t3, r.w);
    } else if (neg) {
        state = -2;                       // all-zero targets
    }
    s_state[tid] = state;
    __syncthreads();

    // ---- phase 2: coalesced float4 sweep over the 256x80 classification tile ----
    const float4* cls4 = reinterpret_cast<const float4*>(
        cls + ((size_t)b * A_ + a0) * C_);
    float cls_partial = 0.0f;
#pragma unroll 4
    for (int it = 0; it < (BLK * C_ / 4) / BLK; ++it) {   // 20 iters
        const int vid  = it * BLK + tid;                  // float4 index in tile
        const float4 v = cls4[vid];
        const int eidx = vid * 4;
        const int al   = eidx / C_;                       // local anchor 0..255
        const int c0   = eidx - al * C_;                  // class of v.x (80%4==0)
        const int st   = s_state[al];
        if (st != -1) {
            cls_partial += focal_term(v.x, st == c0);
            cls_partial += focal_term(v.y, st == c0 + 1);
            cls_partial += focal_term(v.z, st == c0 + 2);
            cls_partial += focal_term(v.w, st == c0 + 3);
        }
    }

    // ---- block reduction: 3 values ----
#pragma unroll
    for (int off = 32; off > 0; off >>= 1) {
        cls_partial += __shfl_down(cls_partial, off);
        reg_partial += __shfl_down(reg_partial, off);
        pos_count   += __shfl_down(pos_count,   off);
    }
    const int wave = tid >> 6;
    if ((tid & 63) == 0) {
        s_red[wave * 3 + 0] = cls_partial;
        s_red[wave * 3 + 1] = reg_partial;
        s_red[wave * 3 + 2] = pos_count;
    }
    __syncthreads();
    if (tid == 0) {
        float c = 0.0f, r = 0.0f, n = 0.0f;
#pragma unroll
        for (int w = 0; w < BLK / 64; ++w) {
            c += s_red[w * 3 + 0];
            r += s_red[w * 3 + 1];
            n += s_red[w * 3 + 2];
        }
        atomicAdd(&acc[b * 3 + 0], c);
        atomicAdd(&acc[b * 3 + 1], r);
        atomicAdd(&acc[b * 3 + 2], n);
    }
}

__global__ void focal_finalize(const float* __restrict__ acc, float* __restrict__ out) {
    const int t = threadIdx.x;
    float cls_l = 0.0f, reg_l = 0.0f;
    if (t < B_) {
        const float np = acc[t * 3 + 2];
        cls_l = acc[t * 3 + 0] / fmaxf(np, 1.0f);
        reg_l = acc[t * 3 + 1] / fmaxf(np * 4.0f, 1.0f);
    }
#pragma unroll
    for (int off = 32; off > 0; off >>= 1) {
        cls_l += __shfl_down(cls_l, off);
        reg_l += __shfl_down(reg_l, off);
    }
    if (t == 0) {
        out[0] = cls_l / (float)B_;
        out[1] = reg_l / (float)B_;
    }
}

extern "C" void kernel_launch(void* const* d_in, const int* in_sizes, int n_in,
                              void* d_out, int out_size, void* d_ws, size_t ws_size,
                              hipStream_t stream) {
    const float* cls     = (const float*)d_in[0];
    const float* regr    = (const float*)d_in[1];
    const float* anchors = (const float*)d_in[2];
    const float* ann     = (const float*)d_in[3];
    const float* negt    = (const float*)d_in[4];
    const float* post    = (const float*)d_in[5];
    float* acc = (float*)d_ws;

    hipMemsetAsync(acc, 0, B_ * 3 * sizeof(float), stream);
    focal_main<<<B_ * (A_ / BLK), BLK, 0, stream>>>(cls, regr, anchors, ann,
                                                    negt, post, acc);
    focal_finalize<<<1, 64, 0, stream>>>(acc, (float*)d_out);
}

// Round 2
// 117.536 us; speedup vs baseline: 1.1171x; 1.1171x over previous
//
#include <hip/hip_runtime.h>

#define B_ 8
#define A_ 98304
#define C_ 80
#define M_ 32
#define BLK 256

// cw for counted anchors: the phase-2 term is  u = p^2 * log2(1-p); loss_neg = 0.75*p^2*(-ln(1-p)) = u * NEGC
#define NEGC (-0.75f * 0.69314718055994531f)

// negative-form core term (must be IDENTICAL in phase 1 correction and phase 2)
__device__ __forceinline__ float neg_u(float praw) {
    const float p = fminf(fmaxf(praw, 1e-4f), 1.0f - 1e-4f);
    return p * p * __log2f(1.0f - p);
}

__device__ __forceinline__ float smooth_l1(float t, float r) {
    float d = fabsf(t - r);
    return (d <= (1.0f / 9.0f)) ? (0.5f * 9.0f * d * d) : (d - 0.5f / 9.0f);
}

__global__ __launch_bounds__(BLK) void focal_main(
    const float* __restrict__ cls,      // [B,A,C]
    const float* __restrict__ regr,     // [B,A,4]
    const float* __restrict__ anchors,  // [A,4]
    const float* __restrict__ ann,      // [B,M,5]
    const float* __restrict__ neg_thr_p,
    const float* __restrict__ pos_thr_p,
    float* __restrict__ acc)            // [B,3] : cls_sum, reg_sum, num_pos
{
    __shared__ float s_x0[M_], s_y0[M_], s_x1[M_], s_y1[M_], s_ab[M_], s_cls[M_];
    __shared__ float s_w[BLK];
    __shared__ float s_red[(BLK / 64) * 3];

    const int tid = threadIdx.x;
    const int blocksPerImg = A_ / BLK;  // 384
    const int b  = blockIdx.x / blocksPerImg;
    const int a0 = (blockIdx.x % blocksPerImg) * BLK;

    if (tid < M_) {
        const float* am = ann + ((size_t)b * M_ + tid) * 5;
        const float x0 = am[0], y0 = am[1], x1 = am[2], y1 = am[3], cl = am[4];
        s_x0[tid] = x0; s_y0[tid] = y0; s_x1[tid] = x1; s_y1[tid] = y1;
        s_ab[tid] = (x1 - x0) * (y1 - y0);
        s_cls[tid] = cl;
    }
    __syncthreads();

    const float neg_thr = neg_thr_p[0];
    const float pos_thr = pos_thr_p[0];

    // ---- phase 1: IoU argmax via cross-multiplication (no divisions) ----
    const int a = a0 + tid;
    const float4 an = reinterpret_cast<const float4*>(anchors)[a];
    const float aw = an.z - an.x;
    const float ah = an.w - an.y;
    const float areaA = aw * ah;

    float ib = -1.0f, ub = 1.0f;   // best inter / best union (iou = ib/ub)
    int   arg = 0;
#pragma unroll
    for (int m = 0; m < M_; ++m) {
        const float iw = fmaxf(fminf(an.z, s_x1[m]) - fmaxf(an.x, s_x0[m]), 0.0f);
        const float ih = fmaxf(fminf(an.w, s_y1[m]) - fmaxf(an.y, s_y0[m]), 0.0f);
        float inter = iw * ih;
        const float ua = fmaxf(areaA + s_ab[m] - inter, 1e-8f);
        if (s_cls[m] == -1.0f) inter = -1.0f;          // invalid annotation -> iou -1
        if (inter * ub > ib * ua) { ib = inter; ub = ua; arg = m; }
    }
    const bool pos = (ib >= pos_thr * ub);
    const bool neg = (ib <  neg_thr * ub);

    float reg_partial = 0.0f;
    float pos_count   = 0.0f;
    float cls_corr    = 0.0f;
    float cw = (pos || neg) ? NEGC : 0.0f;             // ignored anchors contribute 0

    if (pos) {
        pos_count = 1.0f;
        const float gx0 = s_x0[arg], gy0 = s_y0[arg];
        const float gx1 = s_x1[arg], gy1 = s_y1[arg];
        const int   kcls = (int)s_cls[arg];

        // regression loss
        float gw = gx1 - gx0;
        float gh = gy1 - gy0;
        const float gcx = gx0 + 0.5f * gw;
        const float gcy = gy0 + 0.5f * gh;
        gw = fmaxf(gw, 1.0f);
        gh = fmaxf(gh, 1.0f);
        const float acx = an.x + 0.5f * aw;
        const float acy = an.y + 0.5f * ah;
        const float t0 = ((gcx - acx) / aw) * 10.0f;
        const float t1 = ((gcy - acy) / ah) * 10.0f;
        const float t2 = logf(gw / aw) * 5.0f;
        const float t3 = logf(gh / ah) * 5.0f;
        const float4 r = reinterpret_cast<const float4*>(regr)[(size_t)b * A_ + a];
        reg_partial = smooth_l1(t0, r.x) + smooth_l1(t1, r.y) +
                      smooth_l1(t2, r.z) + smooth_l1(t3, r.w);

        // classification correction for the single assigned class:
        // phase 2 will add neg-form for it; replace with pos-form.
        const float praw = cls[((size_t)b * A_ + a) * C_ + kcls];
        const float p  = fminf(fmaxf(praw, 1e-4f), 1.0f - 1e-4f);
        const float om = 1.0f - p;
        const float negv = neg_u(praw) * NEGC;
        const float posv = 0.25f * om * om * (-__logf(p));
        cls_corr = posv - negv;
    }
    s_w[tid] = cw;
    __syncthreads();

    // ---- phase 2: branch-free coalesced float4 sweep (neg-form everywhere) ----
    const float4* cls4 = reinterpret_cast<const float4*>(
        cls + ((size_t)b * A_ + a0) * C_);
    float cls_partial = cls_corr;
#pragma unroll 5
    for (int it = 0; it < (BLK * C_ / 4) / BLK; ++it) {   // 20 iters
        const int vid = it * BLK + tid;                   // float4 index in tile
        const float4 v = cls4[vid];
        const int al = vid / 20;                          // local anchor (80/4 = 20 f4 per row)
        const float cw2 = s_w[al];
        const float u = (neg_u(v.x) + neg_u(v.y)) + (neg_u(v.z) + neg_u(v.w));
        cls_partial = fmaf(u, cw2, cls_partial);
    }

    // ---- block reduction: 3 values ----
#pragma unroll
    for (int off = 32; off > 0; off >>= 1) {
        cls_partial += __shfl_down(cls_partial, off);
        reg_partial += __shfl_down(reg_partial, off);
        pos_count   += __shfl_down(pos_count,   off);
    }
    const int wave = tid >> 6;
    if ((tid & 63) == 0) {
        s_red[wave * 3 + 0] = cls_partial;
        s_red[wave * 3 + 1] = reg_partial;
        s_red[wave * 3 + 2] = pos_count;
    }
    __syncthreads();
    if (tid == 0) {
        float c = 0.0f, r = 0.0f, n = 0.0f;
#pragma unroll
        for (int w = 0; w < BLK / 64; ++w) {
            c += s_red[w * 3 + 0];
            r += s_red[w * 3 + 1];
            n += s_red[w * 3 + 2];
        }
        atomicAdd(&acc[b * 3 + 0], c);
        atomicAdd(&acc[b * 3 + 1], r);
        atomicAdd(&acc[b * 3 + 2], n);
    }
}

__global__ void focal_finalize(const float* __restrict__ acc, float* __restrict__ out) {
    const int t = threadIdx.x;
    float cls_l = 0.0f, reg_l = 0.0f;
    if (t < B_) {
        const float np = acc[t * 3 + 2];
        cls_l = acc[t * 3 + 0] / fmaxf(np, 1.0f);
        reg_l = acc[t * 3 + 1] / fmaxf(np * 4.0f, 1.0f);
    }
#pragma unroll
    for (int off = 32; off > 0; off >>= 1) {
        cls_l += __shfl_down(cls_l, off);
        reg_l += __shfl_down(reg_l, off);
    }
    if (t == 0) {
        out[0] = cls_l / (float)B_;
        out[1] = reg_l / (float)B_;
    }
}

extern "C" void kernel_launch(void* const* d_in, const int* in_sizes, int n_in,
                              void* d_out, int out_size, void* d_ws, size_t ws_size,
                              hipStream_t stream) {
    const float* cls     = (const float*)d_in[0];
    const float* regr    = (const float*)d_in[1];
    const float* anchors = (const float*)d_in[2];
    const float* ann     = (const float*)d_in[3];
    const float* negt    = (const float*)d_in[4];
    const float* post    = (const float*)d_in[5];
    float* acc = (float*)d_ws;

    hipMemsetAsync(acc, 0, B_ * 3 * sizeof(float), stream);
    focal_main<<<B_ * (A_ / BLK), BLK, 0, stream>>>(cls, regr, anchors, ann,
                                                    negt, post, acc);
    focal_finalize<<<1, 64, 0, stream>>>(acc, (float*)d_out);
}